// Round 9
// baseline (280.149 us; speedup 1.0000x reference)
//
#include <hip/hip_runtime.h>
#include <math.h>

#define B_  4096
#define T_  50
#define K_  32
#define D_  64
#define H_  256
#define HL_ 128
#define G4_ 512   // 4*HL

typedef __attribute__((ext_vector_type(8))) short bf16x8;
typedef __attribute__((ext_vector_type(4))) float f32x4;

__device__ __forceinline__ float fast_exp(float x){ return __expf(x); }
__device__ __forceinline__ float fast_rcp(float x){ return __builtin_amdgcn_rcpf(x); }
__device__ __forceinline__ float sigmoidf_(float x){ return fast_rcp(1.f + fast_exp(-x)); }
__device__ __forceinline__ float tanhf_(float x){ return 1.f - 2.f*fast_rcp(1.f + fast_exp(2.f*x)); }

__device__ __forceinline__ short f2bf(float f){
  union { float f; unsigned u; } v; v.f = f;
  unsigned r = v.u + 0x7FFFu + ((v.u >> 16) & 1u);   // round-to-nearest-even
  return (short)(r >> 16);
}
__device__ __forceinline__ float bf2f(short s){
  union { unsigned u; float f; } v; v.u = ((unsigned)(unsigned short)s) << 16;
  return v.f;
}

__device__ __forceinline__ float wave_reduce_sum(float v){
  #pragma unroll
  for (int off = 32; off; off >>= 1) v += __shfl_xor(v, off);
  return v;
}

// ---------------------------------------------------------------------------
// Kernel 1: per-student head (unchanged from R8: float4 loads, interleaved
// DNNs, 4 barriers, MFMA attention).
// ---------------------------------------------------------------------------
#define KROW 72
#define QROW 72
#define PROW 40

__global__ __launch_bounds__(256) void head_kernel(
    const int* __restrict__ uididx, const int* __restrict__ kcodeidx,
    const int* __restrict__ kcode_len, const float* __restrict__ qidemb,
    const int* __restrict__ qid_len, const float* __restrict__ stuE,
    const float* __restrict__ knE,
    const float* __restrict__ T_W1, const float* __restrict__ T_b1,
    const float* __restrict__ T_W2, const float* __restrict__ T_b2,
    const float* __restrict__ A_W1, const float* __restrict__ A_b1,
    const float* __restrict__ A_W2, const float* __restrict__ A_b2,
    short* __restrict__ bvec, float* __restrict__ t_val, float* __restrict__ a_val)
{
  __shared__ __align__(16) short s_kemb[K_*KROW];
  __shared__ __align__(16) short s_kembT[D_*PROW];
  __shared__ __align__(16) short s_q[64*QROW];
  __shared__ __align__(16) short s_p[64*PROW];
  __shared__ float s_stu[D_];
  __shared__ float s_mast[K_];
  __shared__ float s_kmf[K_];
  __shared__ float s_mvec[D_];
  __shared__ float s_avec[D_];
  __shared__ float s_redT[4];
  __shared__ float s_redA[4];

  const int b    = blockIdx.x;
  const int tid  = threadIdx.x;
  const int lane = tid & 63;
  const int w    = tid >> 6;
  const int l15  = lane & 15;
  const int quad = lane >> 4;
  const int klen = kcode_len[b];
  const int qlen = qid_len[b];

  if (tid < D_) s_stu[tid] = stuE[uididx[b]*D_ + tid];
  #pragma unroll
  for (int i = tid; i < 512; i += 256){
    int k = i >> 4, f4 = i & 15;
    const float4 v = *(const float4*)&knE[(size_t)kcodeidx[b*K_ + k]*D_ + f4*4];
    short4 b4; b4.x = f2bf(v.x); b4.y = f2bf(v.y); b4.z = f2bf(v.z); b4.w = f2bf(v.w);
    *(short4*)&s_kemb[k*KROW + f4*4] = b4;
    int d = f4*4;
    s_kembT[(d+0)*PROW + k] = b4.x;
    s_kembT[(d+1)*PROW + k] = b4.y;
    s_kembT[(d+2)*PROW + k] = b4.z;
    s_kembT[(d+3)*PROW + k] = b4.w;
  }
  #pragma unroll
  for (int i = tid; i < 1024; i += 256){
    int t = i >> 4, f4 = i & 15;
    short4 b4;
    if (t < qlen){
      const float4 v = *(const float4*)&qidemb[((size_t)b*T_ + t)*D_ + f4*4];
      b4.x = f2bf(v.x); b4.y = f2bf(v.y); b4.z = f2bf(v.z); b4.w = f2bf(v.w);
    } else { b4.x = 0; b4.y = 0; b4.z = 0; b4.w = 0; }
    *(short4*)&s_q[t*QROW + f4*4] = b4;
  }
  __syncthreads();

  {
    int k = tid >> 3, l8 = tid & 7;
    float s = 0.f;
    #pragma unroll
    for (int j = 0; j < 8; ++j){
      int d = l8 + 8*((j + k) & 7);
      s += s_stu[d] * bf2f(s_kemb[k*KROW + d]);
    }
    s += __shfl_xor(s, 1); s += __shfl_xor(s, 2); s += __shfl_xor(s, 4);
    if (l8 == 0){
      float valid = (k < klen) ? 1.f : 0.f;
      s_mast[k] = valid * sigmoidf_(s * 0.2f);
      s_kmf[k]  = valid;
    }
  }
  __syncthreads();

  if (tid < D_){
    float mv = 0.f, av = 0.f;
    #pragma unroll 4
    for (int k = 0; k < K_; ++k){
      float e = bf2f(s_kemb[k*KROW + tid]);
      mv += s_mast[k] * e;
      av += s_kmf[k]  * e;
    }
    s_mvec[tid] = mv; s_avec[tid] = av;
  }
  __syncthreads();

  // ---- attention via MFMA ----
  {
    f32x4 zero = {0.f, 0.f, 0.f, 0.f};
    f32x4 accs[2] = {zero, zero};
    #pragma unroll
    for (int kt = 0; kt < 2; ++kt){
      bf16x8 aq = *(const bf16x8*)&s_q[(w*16 + l15)*QROW + kt*32 + quad*8];
      #pragma unroll
      for (int nt = 0; nt < 2; ++nt){
        bf16x8 bk = *(const bf16x8*)&s_kemb[(nt*16 + l15)*KROW + kt*32 + quad*8];
        accs[nt] = __builtin_amdgcn_mfma_f32_16x16x32_bf16(aq, bk, accs[nt], 0, 0, 0);
      }
    }
    #pragma unroll
    for (int r = 0; r < 4; ++r){
      float v0 = (l15      < klen) ? accs[0][r]*0.15f : -1e9f;
      float v1 = (l15 + 16 < klen) ? accs[1][r]*0.15f : -1e9f;
      float mx = fmaxf(v0, v1);
      #pragma unroll
      for (int off = 1; off < 16; off <<= 1) mx = fmaxf(mx, __shfl_xor(mx, off));
      float e0 = fast_exp(v0 - mx), e1 = fast_exp(v1 - mx);
      float sm = e0 + e1;
      #pragma unroll
      for (int off = 1; off < 16; off <<= 1) sm += __shfl_xor(sm, off);
      float inv = fast_rcp(sm);
      int row = w*16 + quad*4 + r;
      s_p[row*PROW + l15]      = f2bf(e0 * inv);
      s_p[row*PROW + 16 + l15] = f2bf(e1 * inv);
    }
    bf16x8 ap = *(const bf16x8*)&s_p[(w*16 + l15)*PROW + quad*8];
    #pragma unroll
    for (int nt = 0; nt < 4; ++nt){
      bf16x8 bv = *(const bf16x8*)&s_kembT[(nt*16 + l15)*PROW + quad*8];
      f32x4 acco = __builtin_amdgcn_mfma_f32_16x16x32_bf16(ap, bv, zero, 0, 0, 0);
      #pragma unroll
      for (int r = 0; r < 4; ++r){
        int t = w*16 + quad*4 + r;
        if (t < qlen) bvec[((size_t)b*T_ + t)*D_ + nt*16 + l15] = f2bf(acco[r]);
      }
    }
  }

  // ---- both DNNs interleaved ----
  {
    float accT = T_b1[tid];
    float accA = A_b1[tid];
    #pragma unroll 4
    for (int d = 0; d < D_; ++d){
      float mv = s_mvec[d], av = s_avec[d];
      accT += mv * T_W1[d*H_ + tid];
      accA += av * A_W1[d*H_ + tid];
    }
    float termT = tanhf_(accT) * T_W2[tid];
    float termA = tanhf_(accA) * A_W2[tid];
    termT = wave_reduce_sum(termT);
    termA = wave_reduce_sum(termA);
    if (lane == 0){ s_redT[w] = termT; s_redA[w] = termA; }
    __syncthreads();
    if (tid == 0){
      t_val[b] = s_redT[0] + s_redT[1] + s_redT[2] + s_redT[3] + T_b2[0];
      float v = s_redA[0] + s_redA[1] + s_redA[2] + s_redA[3] + A_b2[0];
      a_val[b] = 8.f * (sigmoidf_(fabsf(v)) - 0.5f);
    }
  }
}

// ---------------------------------------------------------------------------
// Kernel 2: MFMA LSTM. 8 students/block, FULL 512 threads = 8 waves (full
// 512-column coverage — R6's 4-wave version was wrong). grid=512 blocks on
// 256 CUs; VGPR=128 (R8-proven under (512,2)) allows 4 waves/SIMD -> 2
// co-resident blocks/CU = two independent barrier domains filling each
// other's latency bubbles. R5/R8's limiter was grid==CU count, not
// launch_bounds. DO NOT use (512,4): R7 showed it forces a 128-cap the
// structure misses (needs ~160 transiently) -> collapse to 64 + weight spill.
// A-tile M-rows 8..15 zero-padded+masked. c,h in VGPRs; one barrier/step.
// ---------------------------------------------------------------------------
#define AROW 392   // shorts/row: x0(64)|x1(64)|h0(128)|h1(128)|pad(8)

__global__ __launch_bounds__(512, 2) void lstm_kernel(
    const short* __restrict__ bvec, const int* __restrict__ qid_len,
    const float* __restrict__ L_Wi, const float* __restrict__ L_Wh,
    const float* __restrict__ L_b,  const float* __restrict__ L_Wo,
    const float* __restrict__ L_bo, const float* __restrict__ t_val,
    const float* __restrict__ a_val, float* __restrict__ out)
{
  __shared__ __align__(16) short s_A[16*AROW];   // rows 8..15 stay zero
  __shared__ float s_h[16][HL_];
  __shared__ int   s_len[16];

  const int tid  = threadIdx.x;
  const int s0   = blockIdx.x * 8;
  const int w    = tid >> 6;        // 0..7 -> full 512 gate columns
  const int lane = tid & 63;
  const int l15  = lane & 15;
  const int quad = lane >> 4;

  bf16x8 wf[4][6];
  float  biasv[4];
  #pragma unroll
  for (int g = 0; g < 4; ++g){
    const int col = g*128 + w*16 + l15;
    biasv[g] = L_b[col];
    #pragma unroll
    for (int kt = 0; kt < 6; ++kt){
      #pragma unroll
      for (int j = 0; j < 8; ++j){
        int k = kt*32 + quad*8 + j;
        float v = (k < D_) ? L_Wi[k*G4_ + col] : L_Wh[(k-D_)*G4_ + col];
        wf[g][kt][j] = f2bf(v);
      }
    }
  }

  for (int p = tid; p < 16*AROW; p += 512) s_A[p] = 0;
  for (int p = tid; p < 16*HL_; p += 512) (&s_h[0][0])[p] = 0.f;
  if (tid < 16) s_len[tid] = (tid < 8) ? qid_len[s0 + tid] : 0;
  __syncthreads();

  const int xs = tid >> 5, xpos = tid & 31;    // xs 0..15; only xs<8 stage
  if (xs < 8){
    const short2 xv = *(const short2*)&bvec[((size_t)(s0+xs)*T_ + 0)*D_ + xpos*2];
    *(short2*)&s_A[xs*AROW + xpos*2] = xv;
  }
  int maxlen = 0;
  int len_r[4];
  #pragma unroll
  for (int i = 0; i < 8; ++i) maxlen = max(maxlen, s_len[i]);
  #pragma unroll
  for (int r = 0; r < 4; ++r) len_r[r] = s_len[quad*4 + r];   // 0 for rows >= 8
  float c_reg[4] = {0.f,0.f,0.f,0.f};
  float h_reg[4] = {0.f,0.f,0.f,0.f};
  __syncthreads();

  for (int t = 0; t < maxlen; ++t){
    const int xb = t & 1;
    const int hb = xb ^ 1;
    short2 xv;
    const bool havex = (t + 1 < maxlen) && (xs < 8);
    if (havex) xv = *(const short2*)&bvec[((size_t)(s0+xs)*T_ + (t+1))*D_ + xpos*2];

    bf16x8 af[6];
    af[0] = *(const bf16x8*)&s_A[l15*AROW + xb*64 +      quad*8];
    af[1] = *(const bf16x8*)&s_A[l15*AROW + xb*64 + 32 + quad*8];
    #pragma unroll
    for (int kt = 0; kt < 4; ++kt)
      af[2+kt] = *(const bf16x8*)&s_A[l15*AROW + 128 + hb*128 + kt*32 + quad*8];

    f32x4 acc[4];
    #pragma unroll
    for (int g = 0; g < 4; ++g){
      f32x4 a; a[0]=biasv[g]; a[1]=biasv[g]; a[2]=biasv[g]; a[3]=biasv[g];
      acc[g] = a;
    }
    #pragma unroll
    for (int kt = 0; kt < 6; ++kt){
      #pragma unroll
      for (int g = 0; g < 4; ++g)
        acc[g] = __builtin_amdgcn_mfma_f32_16x16x32_bf16(af[kt], wf[g][kt], acc[g], 0, 0, 0);
    }

    if (havex) *(short2*)&s_A[xs*AROW + hb*64 + xpos*2] = xv;

    #pragma unroll
    for (int r = 0; r < 4; ++r){
      if (t < len_r[r]){
        float gi = acc[0][r], gf = acc[1][r], gg = acc[2][r], go = acc[3][r];
        float c2 = sigmoidf_(gf)*c_reg[r] + sigmoidf_(gi)*tanhf_(gg);
        float h2 = sigmoidf_(go)*tanhf_(c2);
        c_reg[r] = c2; h_reg[r] = h2;
        s_h[quad*4 + r][w*16 + l15] = h2;
      }
      s_A[(quad*4 + r)*AROW + 128 + xb*128 + w*16 + l15] = f2bf(h_reg[r]);
    }
    __syncthreads();
  }

  // epilogue: 8 waves, one student each
  {
    int s2 = w;
    float part = s_h[s2][lane]*L_Wo[lane] + s_h[s2][lane+64]*L_Wo[64+lane];
    part = wave_reduce_sum(part);
    if (lane == 0 && s2 < 8){
      float bb = 8.f * (sigmoidf_(part + L_bo[0]) - 0.5f);
      out[s0+s2] = sigmoidf_(a_val[s0+s2] * (t_val[s0+s2] - bb));
    }
  }
}

// ---------------------------------------------------------------------------
extern "C" void kernel_launch(void* const* d_in, const int* in_sizes, int n_in,
                              void* d_out, int out_size, void* d_ws, size_t ws_size,
                              hipStream_t stream)
{
  (void)in_sizes; (void)n_in; (void)out_size; (void)ws_size;
  const int*   uididx    = (const int*)  d_in[0];
  const int*   kcodeidx  = (const int*)  d_in[1];
  const int*   kcode_len = (const int*)  d_in[2];
  const float* qidemb    = (const float*)d_in[3];
  const int*   qid_len   = (const int*)  d_in[4];
  const float* stuE      = (const float*)d_in[5];
  const float* knE       = (const float*)d_in[6];
  const float* T_W1      = (const float*)d_in[7];
  const float* T_b1      = (const float*)d_in[8];
  const float* T_W2      = (const float*)d_in[9];
  const float* T_b2      = (const float*)d_in[10];
  const float* A_W1      = (const float*)d_in[11];
  const float* A_b1      = (const float*)d_in[12];
  const float* A_W2      = (const float*)d_in[13];
  const float* A_b2      = (const float*)d_in[14];
  const float* L_Wi      = (const float*)d_in[15];
  const float* L_Wh      = (const float*)d_in[16];
  const float* L_b       = (const float*)d_in[17];
  const float* L_Wo      = (const float*)d_in[18];
  const float* L_bo      = (const float*)d_in[19];
  float* out = (float*)d_out;

  short* bvec  = (short*)d_ws;                       // B*T*D bf16 = 26.2 MB
  float* t_val = (float*)(bvec + (size_t)B_*T_*D_);  // B floats
  float* a_val = t_val + B_;                         // B floats

  hipLaunchKernelGGL(head_kernel, dim3(B_), dim3(256), 0, stream,
    uididx, kcodeidx, kcode_len, qidemb, qid_len, stuE, knE,
    T_W1, T_b1, T_W2, T_b2, A_W1, A_b1, A_W2, A_b2,
    bvec, t_val, a_val);

  hipLaunchKernelGGL(lstm_kernel, dim3(B_/8), dim3(512), 0, stream,
    bvec, qid_len, L_Wi, L_Wh, L_b, L_Wo, L_bo, t_val, a_val, out);
}

// Round 10
// 227.374 us; speedup vs baseline: 1.2321x; 1.2321x over previous
//
#include <hip/hip_runtime.h>
#include <math.h>

#define B_  4096
#define T_  50
#define K_  32
#define D_  64
#define H_  256
#define HL_ 128
#define G4_ 512   // 4*HL

typedef __attribute__((ext_vector_type(8))) short bf16x8;
typedef __attribute__((ext_vector_type(4))) float f32x4;

__device__ __forceinline__ float fast_exp(float x){ return __expf(x); }
__device__ __forceinline__ float fast_rcp(float x){ return __builtin_amdgcn_rcpf(x); }
__device__ __forceinline__ float sigmoidf_(float x){ return fast_rcp(1.f + fast_exp(-x)); }
__device__ __forceinline__ float tanhf_(float x){ return 1.f - 2.f*fast_rcp(1.f + fast_exp(2.f*x)); }

__device__ __forceinline__ short f2bf(float f){
  union { float f; unsigned u; } v; v.f = f;
  unsigned r = v.u + 0x7FFFu + ((v.u >> 16) & 1u);   // round-to-nearest-even
  return (short)(r >> 16);
}
__device__ __forceinline__ float bf2f(short s){
  union { unsigned u; float f; } v; v.u = ((unsigned)(unsigned short)s) << 16;
  return v.f;
}

__device__ __forceinline__ float wave_reduce_sum(float v){
  #pragma unroll
  for (int off = 32; off; off >>= 1) v += __shfl_xor(v, off);
  return v;
}

// ---------------------------------------------------------------------------
// Kernel 1: per-student head (R8-identical: float4 loads, interleaved DNNs,
// 4 barriers, MFMA attention).
// ---------------------------------------------------------------------------
#define KROW 72
#define QROW 72
#define PROW 40

__global__ __launch_bounds__(256) void head_kernel(
    const int* __restrict__ uididx, const int* __restrict__ kcodeidx,
    const int* __restrict__ kcode_len, const float* __restrict__ qidemb,
    const int* __restrict__ qid_len, const float* __restrict__ stuE,
    const float* __restrict__ knE,
    const float* __restrict__ T_W1, const float* __restrict__ T_b1,
    const float* __restrict__ T_W2, const float* __restrict__ T_b2,
    const float* __restrict__ A_W1, const float* __restrict__ A_b1,
    const float* __restrict__ A_W2, const float* __restrict__ A_b2,
    short* __restrict__ bvec, float* __restrict__ t_val, float* __restrict__ a_val)
{
  __shared__ __align__(16) short s_kemb[K_*KROW];
  __shared__ __align__(16) short s_kembT[D_*PROW];
  __shared__ __align__(16) short s_q[64*QROW];
  __shared__ __align__(16) short s_p[64*PROW];
  __shared__ float s_stu[D_];
  __shared__ float s_mast[K_];
  __shared__ float s_kmf[K_];
  __shared__ float s_mvec[D_];
  __shared__ float s_avec[D_];
  __shared__ float s_redT[4];
  __shared__ float s_redA[4];

  const int b    = blockIdx.x;
  const int tid  = threadIdx.x;
  const int lane = tid & 63;
  const int w    = tid >> 6;
  const int l15  = lane & 15;
  const int quad = lane >> 4;
  const int klen = kcode_len[b];
  const int qlen = qid_len[b];

  if (tid < D_) s_stu[tid] = stuE[uididx[b]*D_ + tid];
  #pragma unroll
  for (int i = tid; i < 512; i += 256){
    int k = i >> 4, f4 = i & 15;
    const float4 v = *(const float4*)&knE[(size_t)kcodeidx[b*K_ + k]*D_ + f4*4];
    short4 b4; b4.x = f2bf(v.x); b4.y = f2bf(v.y); b4.z = f2bf(v.z); b4.w = f2bf(v.w);
    *(short4*)&s_kemb[k*KROW + f4*4] = b4;
    int d = f4*4;
    s_kembT[(d+0)*PROW + k] = b4.x;
    s_kembT[(d+1)*PROW + k] = b4.y;
    s_kembT[(d+2)*PROW + k] = b4.z;
    s_kembT[(d+3)*PROW + k] = b4.w;
  }
  #pragma unroll
  for (int i = tid; i < 1024; i += 256){
    int t = i >> 4, f4 = i & 15;
    short4 b4;
    if (t < qlen){
      const float4 v = *(const float4*)&qidemb[((size_t)b*T_ + t)*D_ + f4*4];
      b4.x = f2bf(v.x); b4.y = f2bf(v.y); b4.z = f2bf(v.z); b4.w = f2bf(v.w);
    } else { b4.x = 0; b4.y = 0; b4.z = 0; b4.w = 0; }
    *(short4*)&s_q[t*QROW + f4*4] = b4;
  }
  __syncthreads();

  {
    int k = tid >> 3, l8 = tid & 7;
    float s = 0.f;
    #pragma unroll
    for (int j = 0; j < 8; ++j){
      int d = l8 + 8*((j + k) & 7);
      s += s_stu[d] * bf2f(s_kemb[k*KROW + d]);
    }
    s += __shfl_xor(s, 1); s += __shfl_xor(s, 2); s += __shfl_xor(s, 4);
    if (l8 == 0){
      float valid = (k < klen) ? 1.f : 0.f;
      s_mast[k] = valid * sigmoidf_(s * 0.2f);
      s_kmf[k]  = valid;
    }
  }
  __syncthreads();

  if (tid < D_){
    float mv = 0.f, av = 0.f;
    #pragma unroll 4
    for (int k = 0; k < K_; ++k){
      float e = bf2f(s_kemb[k*KROW + tid]);
      mv += s_mast[k] * e;
      av += s_kmf[k]  * e;
    }
    s_mvec[tid] = mv; s_avec[tid] = av;
  }
  __syncthreads();

  // ---- attention via MFMA ----
  {
    f32x4 zero = {0.f, 0.f, 0.f, 0.f};
    f32x4 accs[2] = {zero, zero};
    #pragma unroll
    for (int kt = 0; kt < 2; ++kt){
      bf16x8 aq = *(const bf16x8*)&s_q[(w*16 + l15)*QROW + kt*32 + quad*8];
      #pragma unroll
      for (int nt = 0; nt < 2; ++nt){
        bf16x8 bk = *(const bf16x8*)&s_kemb[(nt*16 + l15)*KROW + kt*32 + quad*8];
        accs[nt] = __builtin_amdgcn_mfma_f32_16x16x32_bf16(aq, bk, accs[nt], 0, 0, 0);
      }
    }
    #pragma unroll
    for (int r = 0; r < 4; ++r){
      float v0 = (l15      < klen) ? accs[0][r]*0.15f : -1e9f;
      float v1 = (l15 + 16 < klen) ? accs[1][r]*0.15f : -1e9f;
      float mx = fmaxf(v0, v1);
      #pragma unroll
      for (int off = 1; off < 16; off <<= 1) mx = fmaxf(mx, __shfl_xor(mx, off));
      float e0 = fast_exp(v0 - mx), e1 = fast_exp(v1 - mx);
      float sm = e0 + e1;
      #pragma unroll
      for (int off = 1; off < 16; off <<= 1) sm += __shfl_xor(sm, off);
      float inv = fast_rcp(sm);
      int row = w*16 + quad*4 + r;
      s_p[row*PROW + l15]      = f2bf(e0 * inv);
      s_p[row*PROW + 16 + l15] = f2bf(e1 * inv);
    }
    bf16x8 ap = *(const bf16x8*)&s_p[(w*16 + l15)*PROW + quad*8];
    #pragma unroll
    for (int nt = 0; nt < 4; ++nt){
      bf16x8 bv = *(const bf16x8*)&s_kembT[(nt*16 + l15)*PROW + quad*8];
      f32x4 acco = __builtin_amdgcn_mfma_f32_16x16x32_bf16(ap, bv, zero, 0, 0, 0);
      #pragma unroll
      for (int r = 0; r < 4; ++r){
        int t = w*16 + quad*4 + r;
        if (t < qlen) bvec[((size_t)b*T_ + t)*D_ + nt*16 + l15] = f2bf(acco[r]);
      }
    }
  }

  // ---- both DNNs interleaved ----
  {
    float accT = T_b1[tid];
    float accA = A_b1[tid];
    #pragma unroll 4
    for (int d = 0; d < D_; ++d){
      float mv = s_mvec[d], av = s_avec[d];
      accT += mv * T_W1[d*H_ + tid];
      accA += av * A_W1[d*H_ + tid];
    }
    float termT = tanhf_(accT) * T_W2[tid];
    float termA = tanhf_(accA) * A_W2[tid];
    termT = wave_reduce_sum(termT);
    termA = wave_reduce_sum(termA);
    if (lane == 0){ s_redT[w] = termT; s_redA[w] = termA; }
    __syncthreads();
    if (tid == 0){
      t_val[b] = s_redT[0] + s_redT[1] + s_redT[2] + s_redT[3] + T_b2[0];
      float v = s_redA[0] + s_redA[1] + s_redA[2] + s_redA[3] + A_b2[0];
      a_val[b] = 8.f * (sigmoidf_(fabsf(v)) - 0.5f);
    }
  }
}

// ---------------------------------------------------------------------------
// Kernel 2: MFMA LSTM — R8-exact structure (16 students/block, grid 256,
// (512,2), 70.9 us proven), minus the s_h fp32 shadow copy: epilogue reads
// bf16 h straight from s_A's last-written buffer. Removes 4 conflicted b32
// LDS writes per thread-step (~25% of LDS-pipe write traffic) + 8 KB LDS.
// LESSONS BANKED: (512,4) spills weights (R7); grid 512 w/ 8-wave blocks
// does NOT co-reside (R9 — AGPR acc pushes true regs/wave past 128, HW caps
// at 1 block/CU). This decomposition is 1 block/CU, period.
// ---------------------------------------------------------------------------
#define AROW 392   // shorts/row: x0(64)|x1(64)|h0(128)|h1(128)|pad(8)

__global__ __launch_bounds__(512, 2) void lstm_kernel(
    const short* __restrict__ bvec, const int* __restrict__ qid_len,
    const float* __restrict__ L_Wi, const float* __restrict__ L_Wh,
    const float* __restrict__ L_b,  const float* __restrict__ L_Wo,
    const float* __restrict__ L_bo, const float* __restrict__ t_val,
    const float* __restrict__ a_val, float* __restrict__ out)
{
  __shared__ __align__(16) short s_A[16*AROW];
  __shared__ int s_len[16];

  const int tid  = threadIdx.x;
  const int s0   = blockIdx.x * 16;
  const int w    = tid >> 6;
  const int lane = tid & 63;
  const int l15  = lane & 15;
  const int quad = lane >> 4;

  bf16x8 wf[4][6];
  float  biasv[4];
  #pragma unroll
  for (int g = 0; g < 4; ++g){
    const int col = g*128 + w*16 + l15;
    biasv[g] = L_b[col];
    #pragma unroll
    for (int kt = 0; kt < 6; ++kt){
      #pragma unroll
      for (int j = 0; j < 8; ++j){
        int k = kt*32 + quad*8 + j;
        float v = (k < D_) ? L_Wi[k*G4_ + col] : L_Wh[(k-D_)*G4_ + col];
        wf[g][kt][j] = f2bf(v);
      }
    }
  }

  for (int p = tid; p < 16*AROW; p += 512) s_A[p] = 0;
  if (tid < 16) s_len[tid] = qid_len[s0 + tid];
  __syncthreads();

  const int xs = tid >> 5, xpos = tid & 31;
  {
    const short2 xv = *(const short2*)&bvec[((size_t)(s0+xs)*T_ + 0)*D_ + xpos*2];
    *(short2*)&s_A[xs*AROW + xpos*2] = xv;
  }
  int maxlen = 0;
  int len_r[4];
  #pragma unroll
  for (int i = 0; i < 16; ++i) maxlen = max(maxlen, s_len[i]);
  #pragma unroll
  for (int r = 0; r < 4; ++r) len_r[r] = s_len[quad*4 + r];
  float c_reg[4] = {0.f,0.f,0.f,0.f};
  float h_reg[4] = {0.f,0.f,0.f,0.f};
  __syncthreads();

  for (int t = 0; t < maxlen; ++t){
    const int xb = t & 1;
    const int hb = xb ^ 1;
    short2 xv;
    const bool havex = (t + 1 < maxlen);
    if (havex) xv = *(const short2*)&bvec[((size_t)(s0+xs)*T_ + (t+1))*D_ + xpos*2];

    bf16x8 af[6];
    af[0] = *(const bf16x8*)&s_A[l15*AROW + xb*64 +      quad*8];
    af[1] = *(const bf16x8*)&s_A[l15*AROW + xb*64 + 32 + quad*8];
    #pragma unroll
    for (int kt = 0; kt < 4; ++kt)
      af[2+kt] = *(const bf16x8*)&s_A[l15*AROW + 128 + hb*128 + kt*32 + quad*8];

    f32x4 acc[4];
    #pragma unroll
    for (int g = 0; g < 4; ++g){
      f32x4 a; a[0]=biasv[g]; a[1]=biasv[g]; a[2]=biasv[g]; a[3]=biasv[g];
      acc[g] = a;
    }
    #pragma unroll
    for (int kt = 0; kt < 6; ++kt){
      #pragma unroll
      for (int g = 0; g < 4; ++g)
        acc[g] = __builtin_amdgcn_mfma_f32_16x16x32_bf16(af[kt], wf[g][kt], acc[g], 0, 0, 0);
    }

    if (havex) *(short2*)&s_A[xs*AROW + hb*64 + xpos*2] = xv;

    #pragma unroll
    for (int r = 0; r < 4; ++r){
      if (t < len_r[r]){
        float gi = acc[0][r], gf = acc[1][r], gg = acc[2][r], go = acc[3][r];
        float c2 = sigmoidf_(gf)*c_reg[r] + sigmoidf_(gi)*tanhf_(gg);
        float h2 = sigmoidf_(go)*tanhf_(c2);
        c_reg[r] = c2; h_reg[r] = h2;
      }
      s_A[(quad*4 + r)*AROW + 128 + xb*128 + w*16 + l15] = f2bf(h_reg[r]);
    }
    __syncthreads();
  }

  // epilogue: read bf16 h from the last-written buffer of s_A
  const int xbLast = (maxlen - 1) & 1;
  for (int s2 = w; s2 < 16; s2 += 8){
    float h0 = bf2f(s_A[s2*AROW + 128 + xbLast*128 + lane]);
    float h1 = bf2f(s_A[s2*AROW + 128 + xbLast*128 + 64 + lane]);
    float part = h0*L_Wo[lane] + h1*L_Wo[64+lane];
    part = wave_reduce_sum(part);
    if (lane == 0){
      float bb = 8.f * (sigmoidf_(part + L_bo[0]) - 0.5f);
      out[s0+s2] = sigmoidf_(a_val[s0+s2] * (t_val[s0+s2] - bb));
    }
  }
}

// ---------------------------------------------------------------------------
extern "C" void kernel_launch(void* const* d_in, const int* in_sizes, int n_in,
                              void* d_out, int out_size, void* d_ws, size_t ws_size,
                              hipStream_t stream)
{
  (void)in_sizes; (void)n_in; (void)out_size; (void)ws_size;
  const int*   uididx    = (const int*)  d_in[0];
  const int*   kcodeidx  = (const int*)  d_in[1];
  const int*   kcode_len = (const int*)  d_in[2];
  const float* qidemb    = (const float*)d_in[3];
  const int*   qid_len   = (const int*)  d_in[4];
  const float* stuE      = (const float*)d_in[5];
  const float* knE       = (const float*)d_in[6];
  const float* T_W1      = (const float*)d_in[7];
  const float* T_b1      = (const float*)d_in[8];
  const float* T_W2      = (const float*)d_in[9];
  const float* T_b2      = (const float*)d_in[10];
  const float* A_W1      = (const float*)d_in[11];
  const float* A_b1      = (const float*)d_in[12];
  const float* A_W2      = (const float*)d_in[13];
  const float* A_b2      = (const float*)d_in[14];
  const float* L_Wi      = (const float*)d_in[15];
  const float* L_Wh      = (const float*)d_in[16];
  const float* L_b       = (const float*)d_in[17];
  const float* L_Wo      = (const float*)d_in[18];
  const float* L_bo      = (const float*)d_in[19];
  float* out = (float*)d_out;

  short* bvec  = (short*)d_ws;                       // B*T*D bf16 = 26.2 MB
  float* t_val = (float*)(bvec + (size_t)B_*T_*D_);  // B floats
  float* a_val = t_val + B_;                         // B floats

  hipLaunchKernelGGL(head_kernel, dim3(B_), dim3(256), 0, stream,
    uididx, kcodeidx, kcode_len, qidemb, qid_len, stuE, knE,
    T_W1, T_b1, T_W2, T_b2, A_W1, A_b1, A_W2, A_b2,
    bvec, t_val, a_val);

  hipLaunchKernelGGL(lstm_kernel, dim3(B_/16), dim3(512), 0, stream,
    bvec, qid_len, L_Wi, L_Wh, L_b, L_Wo, L_bo, t_val, a_val, out);
}

// Round 11
// 227.045 us; speedup vs baseline: 1.2339x; 1.0014x over previous
//
#include <hip/hip_runtime.h>
#include <math.h>

#define B_  4096
#define T_  50
#define K_  32
#define D_  64
#define H_  256
#define HL_ 128
#define G4_ 512   // 4*HL

typedef __attribute__((ext_vector_type(8))) short bf16x8;
typedef __attribute__((ext_vector_type(4))) float f32x4;

__device__ __forceinline__ float fast_exp(float x){ return __expf(x); }
__device__ __forceinline__ float fast_rcp(float x){ return __builtin_amdgcn_rcpf(x); }
__device__ __forceinline__ float sigmoidf_(float x){ return fast_rcp(1.f + fast_exp(-x)); }
__device__ __forceinline__ float tanhf_(float x){ return 1.f - 2.f*fast_rcp(1.f + fast_exp(2.f*x)); }

__device__ __forceinline__ short f2bf(float f){
  union { float f; unsigned u; } v; v.f = f;
  unsigned r = v.u + 0x7FFFu + ((v.u >> 16) & 1u);   // round-to-nearest-even
  return (short)(r >> 16);
}
__device__ __forceinline__ float bf2f(short s){
  union { unsigned u; float f; } v; v.u = ((unsigned)(unsigned short)s) << 16;
  return v.f;
}

__device__ __forceinline__ float wave_reduce_sum(float v){
  #pragma unroll
  for (int off = 32; off; off >>= 1) v += __shfl_xor(v, off);
  return v;
}

// ---------------------------------------------------------------------------
// Kernel 1: per-student head (R8/R10-identical: float4 loads, interleaved
// DNNs, 4 barriers, MFMA attention).
// ---------------------------------------------------------------------------
#define KROW 72
#define QROW 72
#define PROW 40

__global__ __launch_bounds__(256) void head_kernel(
    const int* __restrict__ uididx, const int* __restrict__ kcodeidx,
    const int* __restrict__ kcode_len, const float* __restrict__ qidemb,
    const int* __restrict__ qid_len, const float* __restrict__ stuE,
    const float* __restrict__ knE,
    const float* __restrict__ T_W1, const float* __restrict__ T_b1,
    const float* __restrict__ T_W2, const float* __restrict__ T_b2,
    const float* __restrict__ A_W1, const float* __restrict__ A_b1,
    const float* __restrict__ A_W2, const float* __restrict__ A_b2,
    short* __restrict__ bvec, float* __restrict__ t_val, float* __restrict__ a_val)
{
  __shared__ __align__(16) short s_kemb[K_*KROW];
  __shared__ __align__(16) short s_kembT[D_*PROW];
  __shared__ __align__(16) short s_q[64*QROW];
  __shared__ __align__(16) short s_p[64*PROW];
  __shared__ float s_stu[D_];
  __shared__ float s_mast[K_];
  __shared__ float s_kmf[K_];
  __shared__ float s_mvec[D_];
  __shared__ float s_avec[D_];
  __shared__ float s_redT[4];
  __shared__ float s_redA[4];

  const int b    = blockIdx.x;
  const int tid  = threadIdx.x;
  const int lane = tid & 63;
  const int w    = tid >> 6;
  const int l15  = lane & 15;
  const int quad = lane >> 4;
  const int klen = kcode_len[b];
  const int qlen = qid_len[b];

  if (tid < D_) s_stu[tid] = stuE[uididx[b]*D_ + tid];
  #pragma unroll
  for (int i = tid; i < 512; i += 256){
    int k = i >> 4, f4 = i & 15;
    const float4 v = *(const float4*)&knE[(size_t)kcodeidx[b*K_ + k]*D_ + f4*4];
    short4 b4; b4.x = f2bf(v.x); b4.y = f2bf(v.y); b4.z = f2bf(v.z); b4.w = f2bf(v.w);
    *(short4*)&s_kemb[k*KROW + f4*4] = b4;
    int d = f4*4;
    s_kembT[(d+0)*PROW + k] = b4.x;
    s_kembT[(d+1)*PROW + k] = b4.y;
    s_kembT[(d+2)*PROW + k] = b4.z;
    s_kembT[(d+3)*PROW + k] = b4.w;
  }
  #pragma unroll
  for (int i = tid; i < 1024; i += 256){
    int t = i >> 4, f4 = i & 15;
    short4 b4;
    if (t < qlen){
      const float4 v = *(const float4*)&qidemb[((size_t)b*T_ + t)*D_ + f4*4];
      b4.x = f2bf(v.x); b4.y = f2bf(v.y); b4.z = f2bf(v.z); b4.w = f2bf(v.w);
    } else { b4.x = 0; b4.y = 0; b4.z = 0; b4.w = 0; }
    *(short4*)&s_q[t*QROW + f4*4] = b4;
  }
  __syncthreads();

  {
    int k = tid >> 3, l8 = tid & 7;
    float s = 0.f;
    #pragma unroll
    for (int j = 0; j < 8; ++j){
      int d = l8 + 8*((j + k) & 7);
      s += s_stu[d] * bf2f(s_kemb[k*KROW + d]);
    }
    s += __shfl_xor(s, 1); s += __shfl_xor(s, 2); s += __shfl_xor(s, 4);
    if (l8 == 0){
      float valid = (k < klen) ? 1.f : 0.f;
      s_mast[k] = valid * sigmoidf_(s * 0.2f);
      s_kmf[k]  = valid;
    }
  }
  __syncthreads();

  if (tid < D_){
    float mv = 0.f, av = 0.f;
    #pragma unroll 4
    for (int k = 0; k < K_; ++k){
      float e = bf2f(s_kemb[k*KROW + tid]);
      mv += s_mast[k] * e;
      av += s_kmf[k]  * e;
    }
    s_mvec[tid] = mv; s_avec[tid] = av;
  }
  __syncthreads();

  // ---- attention via MFMA ----
  {
    f32x4 zero = {0.f, 0.f, 0.f, 0.f};
    f32x4 accs[2] = {zero, zero};
    #pragma unroll
    for (int kt = 0; kt < 2; ++kt){
      bf16x8 aq = *(const bf16x8*)&s_q[(w*16 + l15)*QROW + kt*32 + quad*8];
      #pragma unroll
      for (int nt = 0; nt < 2; ++nt){
        bf16x8 bk = *(const bf16x8*)&s_kemb[(nt*16 + l15)*KROW + kt*32 + quad*8];
        accs[nt] = __builtin_amdgcn_mfma_f32_16x16x32_bf16(aq, bk, accs[nt], 0, 0, 0);
      }
    }
    #pragma unroll
    for (int r = 0; r < 4; ++r){
      float v0 = (l15      < klen) ? accs[0][r]*0.15f : -1e9f;
      float v1 = (l15 + 16 < klen) ? accs[1][r]*0.15f : -1e9f;
      float mx = fmaxf(v0, v1);
      #pragma unroll
      for (int off = 1; off < 16; off <<= 1) mx = fmaxf(mx, __shfl_xor(mx, off));
      float e0 = fast_exp(v0 - mx), e1 = fast_exp(v1 - mx);
      float sm = e0 + e1;
      #pragma unroll
      for (int off = 1; off < 16; off <<= 1) sm += __shfl_xor(sm, off);
      float inv = fast_rcp(sm);
      int row = w*16 + quad*4 + r;
      s_p[row*PROW + l15]      = f2bf(e0 * inv);
      s_p[row*PROW + 16 + l15] = f2bf(e1 * inv);
    }
    bf16x8 ap = *(const bf16x8*)&s_p[(w*16 + l15)*PROW + quad*8];
    #pragma unroll
    for (int nt = 0; nt < 4; ++nt){
      bf16x8 bv = *(const bf16x8*)&s_kembT[(nt*16 + l15)*PROW + quad*8];
      f32x4 acco = __builtin_amdgcn_mfma_f32_16x16x32_bf16(ap, bv, zero, 0, 0, 0);
      #pragma unroll
      for (int r = 0; r < 4; ++r){
        int t = w*16 + quad*4 + r;
        if (t < qlen) bvec[((size_t)b*T_ + t)*D_ + nt*16 + l15] = f2bf(acco[r]);
      }
    }
  }

  // ---- both DNNs interleaved ----
  {
    float accT = T_b1[tid];
    float accA = A_b1[tid];
    #pragma unroll 4
    for (int d = 0; d < D_; ++d){
      float mv = s_mvec[d], av = s_avec[d];
      accT += mv * T_W1[d*H_ + tid];
      accA += av * A_W1[d*H_ + tid];
    }
    float termT = tanhf_(accT) * T_W2[tid];
    float termA = tanhf_(accA) * A_W2[tid];
    termT = wave_reduce_sum(termT);
    termA = wave_reduce_sum(termA);
    if (lane == 0){ s_redT[w] = termT; s_redA[w] = termA; }
    __syncthreads();
    if (tid == 0){
      t_val[b] = s_redT[0] + s_redT[1] + s_redT[2] + s_redT[3] + T_b2[0];
      float v = s_redA[0] + s_redA[1] + s_redA[2] + s_redA[3] + A_b2[0];
      a_val[b] = 8.f * (sigmoidf_(fabsf(v)) - 0.5f);
    }
  }
}

// ---------------------------------------------------------------------------
// Kernel 2: MFMA LSTM — R10 structure with two latency fixes:
// (1) REGISTER-HELD x prefetch, one-step distance: x(t+1) is loaded during
//     step t-1 and stored to LDS at the TOP of step t, so the compiler's
//     vmcnt wait covers a load with a full step (~1400ns) of slack — HBM/L2
//     miss latency (R10: store-before-barrier put it on the critical path)
//     leaves the per-step critical path. Load of x(t+2) issues right after.
// (2) AROW 392 -> 408 (816B row stride = 204 dw = 12 mod 32): the 4 h-write
//     rows land on disjoint bank groups {0,12,24,4} -> h-writes conflict-
//     free (R10: 2.32e6 conflict cycles); A-frag b128 reads stay 2-way=free.
// LESSONS BANKED: (512,2)+16 students is the only non-spilling shape
// (R7: (512,4) collapses to 64 VGPR; R9: 8-student blocks don't co-reside
// — AGPR acc pushes true regs/wave past 128 -> 1 block/CU regardless).
// ---------------------------------------------------------------------------
#define AROW 408   // shorts/row: x0(64)|x1(64)|h0(128)|h1(128)|pad(24)

__global__ __launch_bounds__(512, 2) void lstm_kernel(
    const short* __restrict__ bvec, const int* __restrict__ qid_len,
    const float* __restrict__ L_Wi, const float* __restrict__ L_Wh,
    const float* __restrict__ L_b,  const float* __restrict__ L_Wo,
    const float* __restrict__ L_bo, const float* __restrict__ t_val,
    const float* __restrict__ a_val, float* __restrict__ out)
{
  __shared__ __align__(16) short s_A[16*AROW];
  __shared__ int s_len[16];

  const int tid  = threadIdx.x;
  const int s0   = blockIdx.x * 16;
  const int w    = tid >> 6;
  const int lane = tid & 63;
  const int l15  = lane & 15;
  const int quad = lane >> 4;

  bf16x8 wf[4][6];
  float  biasv[4];
  #pragma unroll
  for (int g = 0; g < 4; ++g){
    const int col = g*128 + w*16 + l15;
    biasv[g] = L_b[col];
    #pragma unroll
    for (int kt = 0; kt < 6; ++kt){
      #pragma unroll
      for (int j = 0; j < 8; ++j){
        int k = kt*32 + quad*8 + j;
        float v = (k < D_) ? L_Wi[k*G4_ + col] : L_Wh[(k-D_)*G4_ + col];
        wf[g][kt][j] = f2bf(v);
      }
    }
  }

  for (int p = tid; p < 16*AROW; p += 512) s_A[p] = 0;
  if (tid < 16) s_len[tid] = qid_len[s0 + tid];
  __syncthreads();

  const int xs = tid >> 5, xpos = tid & 31;
  {
    const short2 xv = *(const short2*)&bvec[((size_t)(s0+xs)*T_ + 0)*D_ + xpos*2];
    *(short2*)&s_A[xs*AROW + xpos*2] = xv;
  }
  int maxlen = 0;
  int len_r[4];
  #pragma unroll
  for (int i = 0; i < 16; ++i) maxlen = max(maxlen, s_len[i]);
  #pragma unroll
  for (int r = 0; r < 4; ++r) len_r[r] = s_len[quad*4 + r];
  float c_reg[4] = {0.f,0.f,0.f,0.f};
  float h_reg[4] = {0.f,0.f,0.f,0.f};

  // prime the register prefetch with x(1)
  short2 xv_reg;
  if (1 < maxlen) xv_reg = *(const short2*)&bvec[((size_t)(s0+xs)*T_ + 1)*D_ + xpos*2];
  __syncthreads();

  for (int t = 0; t < maxlen; ++t){
    const int xb = t & 1;
    const int hb = xb ^ 1;
    // store x(t+1) — loaded a full step ago, vmcnt wait is slack-covered
    if (t + 1 < maxlen) *(short2*)&s_A[xs*AROW + hb*64 + xpos*2] = xv_reg;
    // issue load of x(t+2); drains across this step and the next
    if (t + 2 < maxlen)
      xv_reg = *(const short2*)&bvec[((size_t)(s0+xs)*T_ + (t+2))*D_ + xpos*2];

    bf16x8 af[6];
    af[0] = *(const bf16x8*)&s_A[l15*AROW + xb*64 +      quad*8];
    af[1] = *(const bf16x8*)&s_A[l15*AROW + xb*64 + 32 + quad*8];
    #pragma unroll
    for (int kt = 0; kt < 4; ++kt)
      af[2+kt] = *(const bf16x8*)&s_A[l15*AROW + 128 + hb*128 + kt*32 + quad*8];

    f32x4 acc[4];
    #pragma unroll
    for (int g = 0; g < 4; ++g){
      f32x4 a; a[0]=biasv[g]; a[1]=biasv[g]; a[2]=biasv[g]; a[3]=biasv[g];
      acc[g] = a;
    }
    #pragma unroll
    for (int kt = 0; kt < 6; ++kt){
      #pragma unroll
      for (int g = 0; g < 4; ++g)
        acc[g] = __builtin_amdgcn_mfma_f32_16x16x32_bf16(af[kt], wf[g][kt], acc[g], 0, 0, 0);
    }

    #pragma unroll
    for (int r = 0; r < 4; ++r){
      if (t < len_r[r]){
        float gi = acc[0][r], gf = acc[1][r], gg = acc[2][r], go = acc[3][r];
        float c2 = sigmoidf_(gf)*c_reg[r] + sigmoidf_(gi)*tanhf_(gg);
        float h2 = sigmoidf_(go)*tanhf_(c2);
        c_reg[r] = c2; h_reg[r] = h2;
      }
      s_A[(quad*4 + r)*AROW + 128 + xb*128 + w*16 + l15] = f2bf(h_reg[r]);
    }
    __syncthreads();
  }

  // epilogue: read bf16 h from the last-written buffer of s_A
  const int xbLast = (maxlen - 1) & 1;
  for (int s2 = w; s2 < 16; s2 += 8){
    float h0 = bf2f(s_A[s2*AROW + 128 + xbLast*128 + lane]);
    float h1 = bf2f(s_A[s2*AROW + 128 + xbLast*128 + 64 + lane]);
    float part = h0*L_Wo[lane] + h1*L_Wo[64+lane];
    part = wave_reduce_sum(part);
    if (lane == 0){
      float bb = 8.f * (sigmoidf_(part + L_bo[0]) - 0.5f);
      out[s0+s2] = sigmoidf_(a_val[s0+s2] * (t_val[s0+s2] - bb));
    }
  }
}

// ---------------------------------------------------------------------------
extern "C" void kernel_launch(void* const* d_in, const int* in_sizes, int n_in,
                              void* d_out, int out_size, void* d_ws, size_t ws_size,
                              hipStream_t stream)
{
  (void)in_sizes; (void)n_in; (void)out_size; (void)ws_size;
  const int*   uididx    = (const int*)  d_in[0];
  const int*   kcodeidx  = (const int*)  d_in[1];
  const int*   kcode_len = (const int*)  d_in[2];
  const float* qidemb    = (const float*)d_in[3];
  const int*   qid_len   = (const int*)  d_in[4];
  const float* stuE      = (const float*)d_in[5];
  const float* knE       = (const float*)d_in[6];
  const float* T_W1      = (const float*)d_in[7];
  const float* T_b1      = (const float*)d_in[8];
  const float* T_W2      = (const float*)d_in[9];
  const float* T_b2      = (const float*)d_in[10];
  const float* A_W1      = (const float*)d_in[11];
  const float* A_b1      = (const float*)d_in[12];
  const float* A_W2      = (const float*)d_in[13];
  const float* A_b2      = (const float*)d_in[14];
  const float* L_Wi      = (const float*)d_in[15];
  const float* L_Wh      = (const float*)d_in[16];
  const float* L_b       = (const float*)d_in[17];
  const float* L_Wo      = (const float*)d_in[18];
  const float* L_bo      = (const float*)d_in[19];
  float* out = (float*)d_out;

  short* bvec  = (short*)d_ws;                       // B*T*D bf16 = 26.2 MB
  float* t_val = (float*)(bvec + (size_t)B_*T_*D_);  // B floats
  float* a_val = t_val + B_;                         // B floats

  hipLaunchKernelGGL(head_kernel, dim3(B_), dim3(256), 0, stream,
    uididx, kcodeidx, kcode_len, qidemb, qid_len, stuE, knE,
    T_W1, T_b1, T_W2, T_b2, A_W1, A_b1, A_W2, A_b2,
    bvec, t_val, a_val);

  hipLaunchKernelGGL(lstm_kernel, dim3(B_/16), dim3(512), 0, stream,
    bvec, qid_len, L_Wi, L_Wh, L_b, L_Wo, L_bo, t_val, a_val, out);
}

// Round 12
// 221.569 us; speedup vs baseline: 1.2644x; 1.0247x over previous
//
#include <hip/hip_runtime.h>
#include <math.h>

#define B_  4096
#define T_  50
#define K_  32
#define D_  64
#define H_  256
#define HL_ 128
#define G4_ 512   // 4*HL

typedef __attribute__((ext_vector_type(8))) short bf16x8;
typedef __attribute__((ext_vector_type(4))) float f32x4;

__device__ __forceinline__ float fast_exp(float x){ return __expf(x); }
__device__ __forceinline__ float fast_rcp(float x){ return __builtin_amdgcn_rcpf(x); }
__device__ __forceinline__ float sigmoidf_(float x){ return fast_rcp(1.f + fast_exp(-x)); }
__device__ __forceinline__ float tanhf_(float x){ return 1.f - 2.f*fast_rcp(1.f + fast_exp(2.f*x)); }

__device__ __forceinline__ short f2bf(float f){
  union { float f; unsigned u; } v; v.f = f;
  unsigned r = v.u + 0x7FFFu + ((v.u >> 16) & 1u);   // round-to-nearest-even
  return (short)(r >> 16);
}
__device__ __forceinline__ float bf2f(short s){
  union { unsigned u; float f; } v; v.u = ((unsigned)(unsigned short)s) << 16;
  return v.f;
}

__device__ __forceinline__ float wave_reduce_sum(float v){
  #pragma unroll
  for (int off = 32; off; off >>= 1) v += __shfl_xor(v, off);
  return v;
}

// ---------------------------------------------------------------------------
// Kernel 1: per-student head. vs R11: s_q staging DELETED — the QK A-fragment
// is built directly from global (2x float4 + reg convert). Removes the
// 1024-iter staging loop, 9.2 KB LDS (25->16 KB/block), and its phase.
// q loads sit at the attention site to keep the 84-VGPR live range short.
// ---------------------------------------------------------------------------
#define KROW 72
#define PROW 40

__global__ __launch_bounds__(256) void head_kernel(
    const int* __restrict__ uididx, const int* __restrict__ kcodeidx,
    const int* __restrict__ kcode_len, const float* __restrict__ qidemb,
    const int* __restrict__ qid_len, const float* __restrict__ stuE,
    const float* __restrict__ knE,
    const float* __restrict__ T_W1, const float* __restrict__ T_b1,
    const float* __restrict__ T_W2, const float* __restrict__ T_b2,
    const float* __restrict__ A_W1, const float* __restrict__ A_b1,
    const float* __restrict__ A_W2, const float* __restrict__ A_b2,
    short* __restrict__ bvec, float* __restrict__ t_val, float* __restrict__ a_val)
{
  __shared__ __align__(16) short s_kemb[K_*KROW];
  __shared__ __align__(16) short s_kembT[D_*PROW];
  __shared__ __align__(16) short s_p[64*PROW];
  __shared__ float s_stu[D_];
  __shared__ float s_mast[K_];
  __shared__ float s_kmf[K_];
  __shared__ float s_mvec[D_];
  __shared__ float s_avec[D_];
  __shared__ float s_redT[4];
  __shared__ float s_redA[4];

  const int b    = blockIdx.x;
  const int tid  = threadIdx.x;
  const int lane = tid & 63;
  const int w    = tid >> 6;
  const int l15  = lane & 15;
  const int quad = lane >> 4;
  const int klen = kcode_len[b];
  const int qlen = qid_len[b];

  if (tid < D_) s_stu[tid] = stuE[uididx[b]*D_ + tid];
  #pragma unroll
  for (int i = tid; i < 512; i += 256){
    int k = i >> 4, f4 = i & 15;
    const float4 v = *(const float4*)&knE[(size_t)kcodeidx[b*K_ + k]*D_ + f4*4];
    short4 b4; b4.x = f2bf(v.x); b4.y = f2bf(v.y); b4.z = f2bf(v.z); b4.w = f2bf(v.w);
    *(short4*)&s_kemb[k*KROW + f4*4] = b4;
    int d = f4*4;
    s_kembT[(d+0)*PROW + k] = b4.x;
    s_kembT[(d+1)*PROW + k] = b4.y;
    s_kembT[(d+2)*PROW + k] = b4.z;
    s_kembT[(d+3)*PROW + k] = b4.w;
  }
  __syncthreads();

  // mastery: 8 lanes per k, bank-rotated
  {
    int k = tid >> 3, l8 = tid & 7;
    float s = 0.f;
    #pragma unroll
    for (int j = 0; j < 8; ++j){
      int d = l8 + 8*((j + k) & 7);
      s += s_stu[d] * bf2f(s_kemb[k*KROW + d]);
    }
    s += __shfl_xor(s, 1); s += __shfl_xor(s, 2); s += __shfl_xor(s, 4);
    if (l8 == 0){
      float valid = (k < klen) ? 1.f : 0.f;
      s_mast[k] = valid * sigmoidf_(s * 0.2f);
      s_kmf[k]  = valid;
    }
  }
  __syncthreads();

  if (tid < D_){
    float mv = 0.f, av = 0.f;
    #pragma unroll 4
    for (int k = 0; k < K_; ++k){
      float e = bf2f(s_kemb[k*KROW + tid]);
      mv += s_mast[k] * e;
      av += s_kmf[k]  * e;
    }
    s_mvec[tid] = mv; s_avec[tid] = av;
  }
  __syncthreads();

  // ---- attention via MFMA; q A-frags straight from global ----
  {
    const int qrow = w*16 + l15;
    bf16x8 aq[2];
    #pragma unroll
    for (int kt = 0; kt < 2; ++kt){
      if (qrow < qlen){
        const float4 v0 = *(const float4*)&qidemb[((size_t)b*T_ + qrow)*D_ + kt*32 + quad*8];
        const float4 v1 = *(const float4*)&qidemb[((size_t)b*T_ + qrow)*D_ + kt*32 + quad*8 + 4];
        aq[kt][0]=f2bf(v0.x); aq[kt][1]=f2bf(v0.y); aq[kt][2]=f2bf(v0.z); aq[kt][3]=f2bf(v0.w);
        aq[kt][4]=f2bf(v1.x); aq[kt][5]=f2bf(v1.y); aq[kt][6]=f2bf(v1.z); aq[kt][7]=f2bf(v1.w);
      } else {
        aq[kt][0]=0; aq[kt][1]=0; aq[kt][2]=0; aq[kt][3]=0;
        aq[kt][4]=0; aq[kt][5]=0; aq[kt][6]=0; aq[kt][7]=0;
      }
    }
    f32x4 zero = {0.f, 0.f, 0.f, 0.f};
    f32x4 accs[2] = {zero, zero};
    #pragma unroll
    for (int kt = 0; kt < 2; ++kt){
      #pragma unroll
      for (int nt = 0; nt < 2; ++nt){
        bf16x8 bk = *(const bf16x8*)&s_kemb[(nt*16 + l15)*KROW + kt*32 + quad*8];
        accs[nt] = __builtin_amdgcn_mfma_f32_16x16x32_bf16(aq[kt], bk, accs[nt], 0, 0, 0);
      }
    }
    #pragma unroll
    for (int r = 0; r < 4; ++r){
      float v0 = (l15      < klen) ? accs[0][r]*0.15f : -1e9f;
      float v1 = (l15 + 16 < klen) ? accs[1][r]*0.15f : -1e9f;
      float mx = fmaxf(v0, v1);
      #pragma unroll
      for (int off = 1; off < 16; off <<= 1) mx = fmaxf(mx, __shfl_xor(mx, off));
      float e0 = fast_exp(v0 - mx), e1 = fast_exp(v1 - mx);
      float sm = e0 + e1;
      #pragma unroll
      for (int off = 1; off < 16; off <<= 1) sm += __shfl_xor(sm, off);
      float inv = fast_rcp(sm);
      int row = w*16 + quad*4 + r;
      s_p[row*PROW + l15]      = f2bf(e0 * inv);
      s_p[row*PROW + 16 + l15] = f2bf(e1 * inv);
    }
    bf16x8 ap = *(const bf16x8*)&s_p[(w*16 + l15)*PROW + quad*8];
    #pragma unroll
    for (int nt = 0; nt < 4; ++nt){
      bf16x8 bv = *(const bf16x8*)&s_kembT[(nt*16 + l15)*PROW + quad*8];
      f32x4 acco = __builtin_amdgcn_mfma_f32_16x16x32_bf16(ap, bv, zero, 0, 0, 0);
      #pragma unroll
      for (int r = 0; r < 4; ++r){
        int t = w*16 + quad*4 + r;
        if (t < qlen) bvec[((size_t)b*T_ + t)*D_ + nt*16 + l15] = f2bf(acco[r]);
      }
    }
  }

  // ---- both DNNs interleaved ----
  {
    float accT = T_b1[tid];
    float accA = A_b1[tid];
    #pragma unroll 4
    for (int d = 0; d < D_; ++d){
      float mv = s_mvec[d], av = s_avec[d];
      accT += mv * T_W1[d*H_ + tid];
      accA += av * A_W1[d*H_ + tid];
    }
    float termT = tanhf_(accT) * T_W2[tid];
    float termA = tanhf_(accA) * A_W2[tid];
    termT = wave_reduce_sum(termT);
    termA = wave_reduce_sum(termA);
    if (lane == 0){ s_redT[w] = termT; s_redA[w] = termA; }
    __syncthreads();
    if (tid == 0){
      t_val[b] = s_redT[0] + s_redT[1] + s_redT[2] + s_redT[3] + T_b2[0];
      float v = s_redA[0] + s_redA[1] + s_redA[2] + s_redA[3] + A_b2[0];
      a_val[b] = 8.f * (sigmoidf_(fabsf(v)) - 0.5f);
    }
  }
}

// ---------------------------------------------------------------------------
// Kernel 2: MFMA LSTM — R11-frozen (69 us stable). 16 students/block, grid
// 256, (512,2), gate-major weights in 96 VGPR, c/h in regs, one barrier/step,
// register x-prefetch. PLATEAU EVIDENCE: R10 padding, R11 prefetch+stride all
// neutral (conflicts bit-identical 2.32e6) — the ~3400 cyc/step is the
// vmcnt-drain + all-to-all h-exchange barrier, structural to this K-loop.
// ---------------------------------------------------------------------------
#define AROW 408   // shorts/row: x0(64)|x1(64)|h0(128)|h1(128)|pad(24)

__global__ __launch_bounds__(512, 2) void lstm_kernel(
    const short* __restrict__ bvec, const int* __restrict__ qid_len,
    const float* __restrict__ L_Wi, const float* __restrict__ L_Wh,
    const float* __restrict__ L_b,  const float* __restrict__ L_Wo,
    const float* __restrict__ L_bo, const float* __restrict__ t_val,
    const float* __restrict__ a_val, float* __restrict__ out)
{
  __shared__ __align__(16) short s_A[16*AROW];
  __shared__ int s_len[16];

  const int tid  = threadIdx.x;
  const int s0   = blockIdx.x * 16;
  const int w    = tid >> 6;
  const int lane = tid & 63;
  const int l15  = lane & 15;
  const int quad = lane >> 4;

  bf16x8 wf[4][6];
  float  biasv[4];
  #pragma unroll
  for (int g = 0; g < 4; ++g){
    const int col = g*128 + w*16 + l15;
    biasv[g] = L_b[col];
    #pragma unroll
    for (int kt = 0; kt < 6; ++kt){
      #pragma unroll
      for (int j = 0; j < 8; ++j){
        int k = kt*32 + quad*8 + j;
        float v = (k < D_) ? L_Wi[k*G4_ + col] : L_Wh[(k-D_)*G4_ + col];
        wf[g][kt][j] = f2bf(v);
      }
    }
  }

  for (int p = tid; p < 16*AROW; p += 512) s_A[p] = 0;
  if (tid < 16) s_len[tid] = qid_len[s0 + tid];
  __syncthreads();

  const int xs = tid >> 5, xpos = tid & 31;
  {
    const short2 xv = *(const short2*)&bvec[((size_t)(s0+xs)*T_ + 0)*D_ + xpos*2];
    *(short2*)&s_A[xs*AROW + xpos*2] = xv;
  }
  int maxlen = 0;
  int len_r[4];
  #pragma unroll
  for (int i = 0; i < 16; ++i) maxlen = max(maxlen, s_len[i]);
  #pragma unroll
  for (int r = 0; r < 4; ++r) len_r[r] = s_len[quad*4 + r];
  float c_reg[4] = {0.f,0.f,0.f,0.f};
  float h_reg[4] = {0.f,0.f,0.f,0.f};

  short2 xv_reg;
  if (1 < maxlen) xv_reg = *(const short2*)&bvec[((size_t)(s0+xs)*T_ + 1)*D_ + xpos*2];
  __syncthreads();

  for (int t = 0; t < maxlen; ++t){
    const int xb = t & 1;
    const int hb = xb ^ 1;
    if (t + 1 < maxlen) *(short2*)&s_A[xs*AROW + hb*64 + xpos*2] = xv_reg;
    if (t + 2 < maxlen)
      xv_reg = *(const short2*)&bvec[((size_t)(s0+xs)*T_ + (t+2))*D_ + xpos*2];

    bf16x8 af[6];
    af[0] = *(const bf16x8*)&s_A[l15*AROW + xb*64 +      quad*8];
    af[1] = *(const bf16x8*)&s_A[l15*AROW + xb*64 + 32 + quad*8];
    #pragma unroll
    for (int kt = 0; kt < 4; ++kt)
      af[2+kt] = *(const bf16x8*)&s_A[l15*AROW + 128 + hb*128 + kt*32 + quad*8];

    f32x4 acc[4];
    #pragma unroll
    for (int g = 0; g < 4; ++g){
      f32x4 a; a[0]=biasv[g]; a[1]=biasv[g]; a[2]=biasv[g]; a[3]=biasv[g];
      acc[g] = a;
    }
    #pragma unroll
    for (int kt = 0; kt < 6; ++kt){
      #pragma unroll
      for (int g = 0; g < 4; ++g)
        acc[g] = __builtin_amdgcn_mfma_f32_16x16x32_bf16(af[kt], wf[g][kt], acc[g], 0, 0, 0);
    }

    #pragma unroll
    for (int r = 0; r < 4; ++r){
      if (t < len_r[r]){
        float gi = acc[0][r], gf = acc[1][r], gg = acc[2][r], go = acc[3][r];
        float c2 = sigmoidf_(gf)*c_reg[r] + sigmoidf_(gi)*tanhf_(gg);
        float h2 = sigmoidf_(go)*tanhf_(c2);
        c_reg[r] = c2; h_reg[r] = h2;
      }
      s_A[(quad*4 + r)*AROW + 128 + xb*128 + w*16 + l15] = f2bf(h_reg[r]);
    }
    __syncthreads();
  }

  const int xbLast = (maxlen - 1) & 1;
  for (int s2 = w; s2 < 16; s2 += 8){
    float h0 = bf2f(s_A[s2*AROW + 128 + xbLast*128 + lane]);
    float h1 = bf2f(s_A[s2*AROW + 128 + xbLast*128 + 64 + lane]);
    float part = h0*L_Wo[lane] + h1*L_Wo[64+lane];
    part = wave_reduce_sum(part);
    if (lane == 0){
      float bb = 8.f * (sigmoidf_(part + L_bo[0]) - 0.5f);
      out[s0+s2] = sigmoidf_(a_val[s0+s2] * (t_val[s0+s2] - bb));
    }
  }
}

// ---------------------------------------------------------------------------
extern "C" void kernel_launch(void* const* d_in, const int* in_sizes, int n_in,
                              void* d_out, int out_size, void* d_ws, size_t ws_size,
                              hipStream_t stream)
{
  (void)in_sizes; (void)n_in; (void)out_size; (void)ws_size;
  const int*   uididx    = (const int*)  d_in[0];
  const int*   kcodeidx  = (const int*)  d_in[1];
  const int*   kcode_len = (const int*)  d_in[2];
  const float* qidemb    = (const float*)d_in[3];
  const int*   qid_len   = (const int*)  d_in[4];
  const float* stuE      = (const float*)d_in[5];
  const float* knE       = (const float*)d_in[6];
  const float* T_W1      = (const float*)d_in[7];
  const float* T_b1      = (const float*)d_in[8];
  const float* T_W2      = (const float*)d_in[9];
  const float* T_b2      = (const float*)d_in[10];
  const float* A_W1      = (const float*)d_in[11];
  const float* A_b1      = (const float*)d_in[12];
  const float* A_W2      = (const float*)d_in[13];
  const float* A_b2      = (const float*)d_in[14];
  const float* L_Wi      = (const float*)d_in[15];
  const float* L_Wh      = (const float*)d_in[16];
  const float* L_b       = (const float*)d_in[17];
  const float* L_Wo      = (const float*)d_in[18];
  const float* L_bo      = (const float*)d_in[19];
  float* out = (float*)d_out;

  short* bvec  = (short*)d_ws;                       // B*T*D bf16 = 26.2 MB
  float* t_val = (float*)(bvec + (size_t)B_*T_*D_);  // B floats
  float* a_val = t_val + B_;                         // B floats

  hipLaunchKernelGGL(head_kernel, dim3(B_), dim3(256), 0, stream,
    uididx, kcodeidx, kcode_len, qidemb, qid_len, stuE, knE,
    T_W1, T_b1, T_W2, T_b2, A_W1, A_b1, A_W2, A_b2,
    bvec, t_val, a_val);

  hipLaunchKernelGGL(lstm_kernel, dim3(B_/16), dim3(512), 0, stream,
    bvec, qid_len, L_Wi, L_Wh, L_b, L_Wo, L_bo, t_val, a_val, out);
}